// Round 14
// baseline (549.954 us; speedup 1.0000x reference)
//
#include <hip/hip_runtime.h>

// DIAGNOSTIC ROUND (x3 idempotent repetition of the R13 kernel body).
// Purpose: three structurally different kernels (R5/R12/R13) all measure
// ~345 us clock-normalized; the kernel dispatch is masked in rocprof top-5
// by ~170us harness fills. This build repeats the full computation 3x
// (reps 0,1 store to d_ws scratch, rep 2 stores to d_out) so that
//   K = (dur14 - dur13)/2  and  OH = dur13 - K
// resolve the kernel-time vs harness-overhead ambiguity, and the 3x kernel
// (>170us) surfaces in top-5 WITH counters (VALUBusy/MfmaUtil/WRITE/FETCH).
// LICM blocked via asm-opaque zero in all addresses; DSE blocked via
// rep-distinct store targets. Output values identical each rep -> correct.

#define N_PTS 131072
#define M_PROT 512
#define D_DIM 64
#define BN 32

typedef __attribute__((ext_vector_type(8))) short short8;
typedef __attribute__((ext_vector_type(4))) float f32x4;

union FragU { uint u[4]; short8 s; };

__device__ inline void load_split(const float* p, short8& hi, short8& lo, float& nrm) {
  const float4 a = *reinterpret_cast<const float4*>(p);
  const float4 b = *reinterpret_cast<const float4*>(p + 4);
  const float f[8] = {a.x, a.y, a.z, a.w, b.x, b.y, b.z, b.w};
  FragU H, L;
#pragma unroll
  for (int i = 0; i < 4; ++i) {
    const uint u0 = __float_as_uint(f[2 * i]);
    const uint u1 = __float_as_uint(f[2 * i + 1]);
    H.u[i] = (u0 >> 16) | (u1 & 0xFFFF0000u);
    const float l0 = f[2 * i]     - __uint_as_float(u0 & 0xFFFF0000u);
    const float l1 = f[2 * i + 1] - __uint_as_float(u1 & 0xFFFF0000u);
    L.u[i] = (__float_as_uint(l0) >> 16) | (__float_as_uint(l1) & 0xFFFF0000u);
    nrm = fmaf(f[2 * i], f[2 * i], nrm);
    nrm = fmaf(f[2 * i + 1], f[2 * i + 1], nrm);
  }
  hi = H.s;
  lo = L.s;
}

__global__ __launch_bounds__(256, 2)
void rbf_mfma_x3(const float* __restrict__ x,
                 const float* __restrict__ prot,
                 float* __restrict__ out,
                 float* __restrict__ ws) {
  __shared__ float T[BN * M_PROT];  // 64 KB staging tile

  const int tid = threadIdx.x;
  const int lane = tid & 63;
  const int w = tid >> 6;
  const int n0 = blockIdx.x * BN;
  const int lr = lane & 15;
  const int kg = (lane >> 4) * 8;
  const int m0w = w * 128;

#pragma unroll 1
  for (int rep = 0; rep < 3; ++rep) {
    // Opaque zero: blocks LICM from hoisting loads/compute out of rep loop.
    int zero = 0;
    asm volatile("" : "+v"(zero));
    const float* xp = x + zero;
    const float* pp = prot + zero;

    f32x4 acc[8][2];
#pragma unroll
    for (int i = 0; i < 8; ++i)
#pragma unroll
      for (int j = 0; j < 2; ++j) acc[i][j] = (f32x4){0.f, 0.f, 0.f, 0.f};

    float ps_part[8] = {0.f, 0.f, 0.f, 0.f, 0.f, 0.f, 0.f, 0.f};
    float xs_part[2] = {0.f, 0.f};

#pragma unroll
    for (int h = 0; h < 2; ++h) {
      short8 XH[2], XL[2];
#pragma unroll
      for (int fj = 0; fj < 2; ++fj)
        load_split(xp + (size_t)(n0 + fj * 16 + lr) * D_DIM + h * 32 + kg,
                   XH[fj], XL[fj], xs_part[fj]);
#pragma unroll
      for (int fi = 0; fi < 8; ++fi) {
        short8 ph, pl;
        load_split(pp + (size_t)(m0w + fi * 16 + lr) * D_DIM + h * 32 + kg,
                   ph, pl, ps_part[fi]);
#pragma unroll
        for (int fj = 0; fj < 2; ++fj) {
          acc[fi][fj] = __builtin_amdgcn_mfma_f32_16x16x32_bf16(ph, XH[fj], acc[fi][fj], 0, 0, 0);
          acc[fi][fj] = __builtin_amdgcn_mfma_f32_16x16x32_bf16(ph, XL[fj], acc[fi][fj], 0, 0, 0);
          acc[fi][fj] = __builtin_amdgcn_mfma_f32_16x16x32_bf16(pl, XH[fj], acc[fi][fj], 0, 0, 0);
        }
      }
    }

#pragma unroll
    for (int fi = 0; fi < 8; ++fi) {
      ps_part[fi] += __shfl_xor(ps_part[fi], 16);
      ps_part[fi] += __shfl_xor(ps_part[fi], 32);
    }
#pragma unroll
    for (int fj = 0; fj < 2; ++fj) {
      xs_part[fj] += __shfl_xor(xs_part[fj], 16);
      xs_part[fj] += __shfl_xor(xs_part[fj], 32);
    }
    const int src = (lane >> 4) * 4;

#pragma unroll
    for (int fi = 0; fi < 8; ++fi) {
      f32x4 psv;
#pragma unroll
      for (int r = 0; r < 4; ++r) psv[r] = __shfl(ps_part[fi], src + r);
#pragma unroll
      for (int fj = 0; fj < 2; ++fj) {
        const f32x4 c = acc[fi][fj];
        const float xsv = xs_part[fj];
        float4 e;
        e.x = __expf(fminf(fmaf(2.f, c[0], -xsv) - psv[0], 0.f));
        e.y = __expf(fminf(fmaf(2.f, c[1], -xsv) - psv[1], 0.f));
        e.z = __expf(fminf(fmaf(2.f, c[2], -xsv) - psv[2], 0.f));
        e.w = __expf(fminf(fmaf(2.f, c[3], -xsv) - psv[3], 0.f));
        const int n_rel = fj * 16 + lr;
        const int m = m0w + fi * 16 + src;
        const int byte = (n_rel * 2048 + m * 4) ^ ((n_rel & 7) << 4);
        *reinterpret_cast<float4*>(reinterpret_cast<char*>(T) + byte) = e;
      }
    }
    __syncthreads();

    // rep 0,1 -> ws (scratch, distinct addresses: blocks DSE); rep 2 -> out.
    float* dst = (rep == 2) ? out : ws + (size_t)rep * BN * M_PROT;
    const size_t outbase = (size_t)n0 * M_PROT;
#pragma unroll
    for (int i = 0; i < 16; ++i) {
      const int fidx = i * 1024 + tid * 4;
      const int n_rel = fidx >> 9;
      const int byte = (fidx * 4) ^ ((n_rel & 7) << 4);
      const float4 v = *reinterpret_cast<const float4*>(reinterpret_cast<const char*>(T) + byte);
      *reinterpret_cast<float4*>(dst + outbase + fidx) = v;
    }
    __syncthreads();  // protect T against next rep's epilogue writes
  }
}

extern "C" void kernel_launch(void* const* d_in, const int* in_sizes, int n_in,
                              void* d_out, int out_size, void* d_ws, size_t ws_size,
                              hipStream_t stream) {
  const float* x = (const float*)d_in[0];
  const float* p = (const float*)d_in[1];
  float* out = (float*)d_out;
  // Scratch target for reps 0,1. Needs ~268MB + 64KB; fills show ws ~1GiB.
  // Fallback: aim at out (values identical -> still correct).
  float* ws = (ws_size >= ((size_t)N_PTS * M_PROT + 2 * BN * M_PROT) * sizeof(float))
                  ? (float*)d_ws : out;
  (void)in_sizes; (void)n_in; (void)out_size;
  rbf_mfma_x3<<<N_PTS / BN, 256, 0, stream>>>(x, p, out, ws);
}

// Round 16
// 356.748 us; speedup vs baseline: 1.5416x; 1.5416x over previous
//
#include <hip/hip_runtime.h>

// RBF: out[n,m] = exp(-max(||x_n||^2 + ||p_m||^2 - 2 x.p, 0)), gamma=1.
// N=131072, M=512, D=64, fp32 in/out.
//
// R14 diagnosis: kernel ~116us, NO pipe saturated (hbm 30%, VALU 33%, MFMA 9%),
// occupancy 22% (64KB LDS -> 2 blocks/CU) => latency-bound; bf16-split VALU
// redundantly recomputed per tile (p re-split 4096x).
// R15/16: (1) pre-split p and x into bf16 hi/lo + norms via two cheap
// pre-kernels (workspace); (2) main kernel = pure short8 loads + MFMA + exp +
// 32KB-LDS half-tile flush => up to 5 blocks/CU (occupancy ~50%).

#define N_PTS 131072
#define M_PROT 512
#define D_DIM 64
#define BN 32

typedef __attribute__((ext_vector_type(8))) short short8;
typedef __attribute__((ext_vector_type(4))) float f32x4;

// ---------------- pre-pass A: split prototypes + ps ----------------
__global__ __launch_bounds__(256) void split_p(const float* __restrict__ p,
                                               ushort* __restrict__ ph,
                                               ushort* __restrict__ pl,
                                               float* __restrict__ ps) {
  const int row = blockIdx.x * 4 + (threadIdx.x >> 6);  // 128 blocks x 4 waves
  const int d = threadIdx.x & 63;
  const float v = p[row * D_DIM + d];
  const uint u = __float_as_uint(v);
  const float hf = __uint_as_float(u & 0xFFFF0000u);
  ph[row * D_DIM + d] = (ushort)(u >> 16);
  pl[row * D_DIM + d] = (ushort)(__float_as_uint(v - hf) >> 16);
  float s = v * v;
  s += __shfl_xor(s, 1);  s += __shfl_xor(s, 2);  s += __shfl_xor(s, 4);
  s += __shfl_xor(s, 8);  s += __shfl_xor(s, 16); s += __shfl_xor(s, 32);
  if (d == 0) ps[row] = s;
}

// ---------------- pre-pass B: split x + xs ----------------
__global__ __launch_bounds__(256) void split_x(const float* __restrict__ x,
                                               ushort* __restrict__ xh,
                                               ushort* __restrict__ xl,
                                               float* __restrict__ xs) {
  const int gid = blockIdx.x * 256 + threadIdx.x;  // 8 threads/row, 8 floats each
  const int row = gid >> 3;
  const int c0 = (gid & 7) * 8;
  const float4 a = *reinterpret_cast<const float4*>(x + (size_t)row * D_DIM + c0);
  const float4 b = *reinterpret_cast<const float4*>(x + (size_t)row * D_DIM + c0 + 4);
  const float f[8] = {a.x, a.y, a.z, a.w, b.x, b.y, b.z, b.w};
  union { uint u[4]; short8 s; } H, L;
  float part = 0.f;
#pragma unroll
  for (int i = 0; i < 4; ++i) {
    const uint u0 = __float_as_uint(f[2 * i]);
    const uint u1 = __float_as_uint(f[2 * i + 1]);
    H.u[i] = (u0 >> 16) | (u1 & 0xFFFF0000u);
    const float l0 = f[2 * i]     - __uint_as_float(u0 & 0xFFFF0000u);
    const float l1 = f[2 * i + 1] - __uint_as_float(u1 & 0xFFFF0000u);
    L.u[i] = (__float_as_uint(l0) >> 16) | (__float_as_uint(l1) & 0xFFFF0000u);
    part = fmaf(f[2 * i], f[2 * i], part);
    part = fmaf(f[2 * i + 1], f[2 * i + 1], part);
  }
  *reinterpret_cast<short8*>(xh + (size_t)row * D_DIM + c0) = H.s;
  *reinterpret_cast<short8*>(xl + (size_t)row * D_DIM + c0) = L.s;
  part += __shfl_xor(part, 1); part += __shfl_xor(part, 2); part += __shfl_xor(part, 4);
  if ((threadIdx.x & 7) == 0) xs[row] = part;
}

// ---------------- main kernel ----------------
__global__ __launch_bounds__(256, 4)
void rbf_main(const ushort* __restrict__ xh, const ushort* __restrict__ xl,
              const ushort* __restrict__ ph, const ushort* __restrict__ pl,
              const float* __restrict__ xs, const float* __restrict__ ps,
              float* __restrict__ out) {
  __shared__ float T[16 * M_PROT];  // 32 KB half-tile -> 5 blocks/CU by LDS

  const int tid = threadIdx.x;
  const int lane = tid & 63;
  const int w = tid >> 6;          // wave owns m-slice [w*128, w*128+128)
  const int n0 = blockIdx.x * BN;
  const int lr = lane & 15;
  const int kg = (lane >> 4) * 8;
  const int m0w = w * 128;
  const int src = (lane >> 4) * 4;

  // x fragments: 8 x short8 (XH/XL [h][fj])
  short8 XH[2][2], XL[2][2];
#pragma unroll
  for (int h = 0; h < 2; ++h)
#pragma unroll
    for (int fj = 0; fj < 2; ++fj) {
      const size_t off = (size_t)(n0 + fj * 16 + lr) * D_DIM + h * 32 + kg;
      XH[h][fj] = *reinterpret_cast<const short8*>(xh + off);
      XL[h][fj] = *reinterpret_cast<const short8*>(xl + off);
    }

  f32x4 acc[8][2];
#pragma unroll
  for (int i = 0; i < 8; ++i)
#pragma unroll
    for (int j = 0; j < 2; ++j) acc[i][j] = (f32x4){0.f, 0.f, 0.f, 0.f};

#pragma unroll
  for (int h = 0; h < 2; ++h)
#pragma unroll
    for (int fi = 0; fi < 8; ++fi) {
      const size_t off = (size_t)(m0w + fi * 16 + lr) * D_DIM + h * 32 + kg;
      const short8 a = *reinterpret_cast<const short8*>(ph + off);
      const short8 b = *reinterpret_cast<const short8*>(pl + off);
#pragma unroll
      for (int fj = 0; fj < 2; ++fj) {
        acc[fi][fj] = __builtin_amdgcn_mfma_f32_16x16x32_bf16(a, XH[h][fj], acc[fi][fj], 0, 0, 0);
        acc[fi][fj] = __builtin_amdgcn_mfma_f32_16x16x32_bf16(a, XL[h][fj], acc[fi][fj], 0, 0, 0);
        acc[fi][fj] = __builtin_amdgcn_mfma_f32_16x16x32_bf16(b, XH[h][fj], acc[fi][fj], 0, 0, 0);
      }
    }

  const float xsv0 = xs[n0 + lr];
  const float xsv1 = xs[n0 + 16 + lr];

  // epilogue in two 16-row halves through 32KB LDS
#pragma unroll
  for (int fj = 0; fj < 2; ++fj) {
    if (fj) __syncthreads();  // protect T reuse
    const float xsv = fj ? xsv1 : xsv0;
#pragma unroll
    for (int fi = 0; fi < 8; ++fi) {
      const int m = m0w + fi * 16 + src;
      const f32x4 psv = *reinterpret_cast<const f32x4*>(ps + m);  // 16B aligned
      const f32x4 c = acc[fi][fj];
      float4 e;
      e.x = __expf(fminf(fmaf(2.f, c[0], -xsv) - psv[0], 0.f));
      e.y = __expf(fminf(fmaf(2.f, c[1], -xsv) - psv[1], 0.f));
      e.z = __expf(fminf(fmaf(2.f, c[2], -xsv) - psv[2], 0.f));
      e.w = __expf(fminf(fmaf(2.f, c[3], -xsv) - psv[3], 0.f));
      const int byte = (lr * 2048 + m * 4) ^ ((lr & 7) << 4);
      *reinterpret_cast<float4*>(reinterpret_cast<char*>(T) + byte) = e;
    }
    __syncthreads();
    // stream 32KB out as contiguous 1KB-per-wave float4 stores
    const size_t outbase = (size_t)(n0 + fj * 16) * M_PROT;
#pragma unroll
    for (int i = 0; i < 8; ++i) {
      const int fidx = i * 1024 + tid * 4;        // 0..8191 floats
      const int nloc = fidx >> 9;
      const int byte = (fidx * 4) ^ ((nloc & 7) << 4);
      const float4 v = *reinterpret_cast<const float4*>(reinterpret_cast<const char*>(T) + byte);
      *reinterpret_cast<float4*>(out + outbase + fidx) = v;
    }
  }
}

// ---------------- fallback (R13 monolithic, used only if ws too small) ------
union FragUF { uint u[4]; short8 s; };
__device__ inline void load_splitF(const float* p, short8& hi, short8& lo, float& nrm) {
  const float4 a = *reinterpret_cast<const float4*>(p);
  const float4 b = *reinterpret_cast<const float4*>(p + 4);
  const float f[8] = {a.x, a.y, a.z, a.w, b.x, b.y, b.z, b.w};
  FragUF H, L;
#pragma unroll
  for (int i = 0; i < 4; ++i) {
    const uint u0 = __float_as_uint(f[2 * i]);
    const uint u1 = __float_as_uint(f[2 * i + 1]);
    H.u[i] = (u0 >> 16) | (u1 & 0xFFFF0000u);
    const float l0 = f[2 * i]     - __uint_as_float(u0 & 0xFFFF0000u);
    const float l1 = f[2 * i + 1] - __uint_as_float(u1 & 0xFFFF0000u);
    L.u[i] = (__float_as_uint(l0) >> 16) | (__float_as_uint(l1) & 0xFFFF0000u);
    nrm = fmaf(f[2 * i], f[2 * i], nrm);
    nrm = fmaf(f[2 * i + 1], f[2 * i + 1], nrm);
  }
  hi = H.s; lo = L.s;
}
__global__ __launch_bounds__(256, 2)
void rbf_fallback(const float* __restrict__ x, const float* __restrict__ prot,
                  float* __restrict__ out) {
  __shared__ float T[BN * M_PROT];
  const int tid = threadIdx.x, lane = tid & 63, w = tid >> 6;
  const int n0 = blockIdx.x * BN, lr = lane & 15, kg = (lane >> 4) * 8, m0w = w * 128;
  f32x4 acc[8][2];
#pragma unroll
  for (int i = 0; i < 8; ++i)
#pragma unroll
    for (int j = 0; j < 2; ++j) acc[i][j] = (f32x4){0.f, 0.f, 0.f, 0.f};
  float ps_part[8] = {0,0,0,0,0,0,0,0}, xs_part[2] = {0,0};
#pragma unroll
  for (int h = 0; h < 2; ++h) {
    short8 XHf[2], XLf[2];
#pragma unroll
    for (int fj = 0; fj < 2; ++fj)
      load_splitF(x + (size_t)(n0 + fj * 16 + lr) * D_DIM + h * 32 + kg, XHf[fj], XLf[fj], xs_part[fj]);
#pragma unroll
    for (int fi = 0; fi < 8; ++fi) {
      short8 a, b;
      load_splitF(prot + (size_t)(m0w + fi * 16 + lr) * D_DIM + h * 32 + kg, a, b, ps_part[fi]);
#pragma unroll
      for (int fj = 0; fj < 2; ++fj) {
        acc[fi][fj] = __builtin_amdgcn_mfma_f32_16x16x32_bf16(a, XHf[fj], acc[fi][fj], 0, 0, 0);
        acc[fi][fj] = __builtin_amdgcn_mfma_f32_16x16x32_bf16(a, XLf[fj], acc[fi][fj], 0, 0, 0);
        acc[fi][fj] = __builtin_amdgcn_mfma_f32_16x16x32_bf16(b, XHf[fj], acc[fi][fj], 0, 0, 0);
      }
    }
  }
#pragma unroll
  for (int fi = 0; fi < 8; ++fi) {
    ps_part[fi] += __shfl_xor(ps_part[fi], 16); ps_part[fi] += __shfl_xor(ps_part[fi], 32);
  }
#pragma unroll
  for (int fj = 0; fj < 2; ++fj) {
    xs_part[fj] += __shfl_xor(xs_part[fj], 16); xs_part[fj] += __shfl_xor(xs_part[fj], 32);
  }
  const int src = (lane >> 4) * 4;
#pragma unroll
  for (int fi = 0; fi < 8; ++fi) {
    f32x4 psv;
#pragma unroll
    for (int r = 0; r < 4; ++r) psv[r] = __shfl(ps_part[fi], src + r);
#pragma unroll
    for (int fj = 0; fj < 2; ++fj) {
      const f32x4 c = acc[fi][fj];
      const float xsv = xs_part[fj];
      float4 e;
      e.x = __expf(fminf(fmaf(2.f, c[0], -xsv) - psv[0], 0.f));
      e.y = __expf(fminf(fmaf(2.f, c[1], -xsv) - psv[1], 0.f));
      e.z = __expf(fminf(fmaf(2.f, c[2], -xsv) - psv[2], 0.f));
      e.w = __expf(fminf(fmaf(2.f, c[3], -xsv) - psv[3], 0.f));
      const int n_rel = fj * 16 + lr;
      const int m = m0w + fi * 16 + src;
      const int byte = (n_rel * 2048 + m * 4) ^ ((n_rel & 7) << 4);
      *reinterpret_cast<float4*>(reinterpret_cast<char*>(T) + byte) = e;
    }
  }
  __syncthreads();
  const size_t outbase = (size_t)n0 * M_PROT;
#pragma unroll
  for (int i = 0; i < 16; ++i) {
    const int fidx = i * 1024 + tid * 4;
    const int n_rel = fidx >> 9;
    const int byte = (fidx * 4) ^ ((n_rel & 7) << 4);
    const float4 v = *reinterpret_cast<const float4*>(reinterpret_cast<const char*>(T) + byte);
    *reinterpret_cast<float4*>(out + outbase + fidx) = v;
  }
}

extern "C" void kernel_launch(void* const* d_in, const int* in_sizes, int n_in,
                              void* d_out, int out_size, void* d_ws, size_t ws_size,
                              hipStream_t stream) {
  const float* x = (const float*)d_in[0];
  const float* p = (const float*)d_in[1];
  float* out = (float*)d_out;
  (void)in_sizes; (void)n_in; (void)out_size;

  // workspace layout (16B-aligned slabs)
  const size_t xh_off = 0;
  const size_t xl_off = xh_off + (size_t)N_PTS * D_DIM * 2;        // 16 MiB
  const size_t ph_off = xl_off + (size_t)N_PTS * D_DIM * 2;        // +16 MiB
  const size_t pl_off = ph_off + (size_t)M_PROT * D_DIM * 2;       // +64 KiB
  const size_t ps_off = pl_off + (size_t)M_PROT * D_DIM * 2;       // +64 KiB
  const size_t xs_off = ps_off + (size_t)M_PROT * 4;               // +2 KiB
  const size_t need   = xs_off + (size_t)N_PTS * 4;                // +512 KiB

  if (ws_size < need) {  // defensive: self-contained path (R13, verified)
    rbf_fallback<<<N_PTS / BN, 256, 0, stream>>>(x, p, out);
    return;
  }
  char* ws = (char*)d_ws;
  ushort* xh = (ushort*)(ws + xh_off);
  ushort* xl = (ushort*)(ws + xl_off);
  ushort* ph = (ushort*)(ws + ph_off);
  ushort* pl = (ushort*)(ws + pl_off);
  float*  ps = (float*)(ws + ps_off);
  float*  xs = (float*)(ws + xs_off);

  split_p<<<M_PROT / 4, 256, 0, stream>>>(p, ph, pl, ps);
  split_x<<<N_PTS * 8 / 256, 256, 0, stream>>>(x, xh, xl, xs);
  rbf_main<<<N_PTS / BN, 256, 0, stream>>>(xh, xl, ph, pl, xs, ps, out);
}